// Round 1
// baseline (537.777 us; speedup 1.0000x reference)
//
#include <hip/hip_runtime.h>
#include <hip/hip_fp16.h>
#include <math.h>

// LinearCaps2d, BATCH=256, N = B_TYPES*H*W = 2048, C=10, POSE=16, 3 routing iters.
// R13 = R12 occupancy push: everything <25% busy at 2 blocks/CU (grid 512).
//   (1) grid 512 -> 1024: 256 n-groups of 8 n (2 staged l-iters) x 4 b-groups;
//   (2) Ws re-laid as XOR-swizzled [640][16] f16 (20480 B, was 640x28=35840):
//       LDS 45568 -> 30208 B so 4 blocks/CU fit; swizzle is lane-constant on
//       both store and read sides (odd-c rows read col ^ 2, compile-time);
//   (3) __launch_bounds__(256,4) pins VGPR<=128 -> 16 waves/CU;
//   (4) atomic flush doubles in count (256 n-groups); per-address contention
//       held at 128 via dual accumulator copies (ngrp parity), consumers sum
//       both copies at load (sS=0.5 same-buffer fallback if ws too small).
// ws: 2 copies each of s0,s1,s2 [40960] f32 = 983 KB.

typedef _Float16 f16;
typedef _Float16 f16x2 __attribute__((ext_vector_type(2)));
typedef _Float16 f16x4 __attribute__((ext_vector_type(4)));
typedef __fp16   h16x2 __attribute__((ext_vector_type(2)));
typedef float f32x4 __attribute__((ext_vector_type(4)));

__device__ __forceinline__ f16x2 pk(float a, float b) {
    h16x2 t = __builtin_amdgcn_cvt_pkrtz(a, b);
    return __builtin_bit_cast(f16x2, t);
}

#if __has_builtin(__builtin_amdgcn_fdot2)
__device__ __forceinline__ float FDOT2(f16x2 a, f16x2 b, float c) {
    return __builtin_amdgcn_fdot2(__builtin_bit_cast(h16x2, a),
                                  __builtin_bit_cast(h16x2, b), c, false);
}
#else
__device__ __forceinline__ float FDOT2(f16x2 a, f16x2 b, float c) {
    return c + (float)a[0] * (float)b[0] + (float)a[1] * (float)b[1];
}
#endif

constexpr int XS_ROW = 76;   // f16 row stride (4n x 16 i + pad)

__device__ __forceinline__ float xorsum4(float v) {
    v += __shfl_xor(v, 16, 64);
    v += __shfl_xor(v, 32, 64);
    return v;
}

// packed f16x2 cross-quad reduction: one shfl pair for two c's (verified R11)
__device__ __forceinline__ f16x2 xorsum4h(f16x2 v) {
    union { f16x2 h; int i; } u;
    union { int i; f16x2 h; } w;
    u.h = v; w.i = __shfl_xor(u.i, 16, 64); v = v + w.h;
    u.h = v; w.i = __shfl_xor(u.i, 32, 64); v = v + w.h;
    return v;
}

__device__ __forceinline__ f16x4 cvt4(float4 w) {
    f16x2 a = pk(w.x, w.y);
    f16x2 b = pk(w.z, w.w);
    f16x4 r; r[0] = a[0]; r[1] = a[1]; r[2] = b[0]; r[3] = b[1];
    return r;
}

// grid: 1024 blocks = 256 n-groups (8 n) x 4 b-groups (64 b); 256 thr = 4 waves.
template<int PASS>
__global__ __launch_bounds__(256, 4)
void pass_k(const float* __restrict__ poses, const float* __restrict__ weight,
            const float* __restrict__ bias,
            const float* __restrict__ sp0a, const float* __restrict__ sp0b,
            const float* __restrict__ sp1a, const float* __restrict__ sp1b,
            float* __restrict__ s_base, int dsel, float sS)
{
    __shared__ f16 Ws[640 * 16];       // 20480 B, XOR-swizzled columns
    __shared__ f16 xs[64 * XS_ROW];    //  9728 B

    const int tid  = threadIdx.x;
    const int blk  = blockIdx.x;
    const int ngrp = blk >> 2;          // 256 n-groups (8 n each)
    const int b0   = (blk & 3) * 64;    // 4 b-groups
    const int wave = tid >> 6;
    const int lane = tid & 63;
    const int q    = lane >> 4;
    const int lo   = lane & 15;
    const int wtb  = wave * 16;
    const int bg   = b0 + wtb;          // wave's global batch base

    float* s_dst = s_base + (ngrp & 1) * dsel;   // dual accumulator copies

    // swizzle constants (lane-constant): physical col-quad = q ^ sigma(row),
    // sigma(row) = ((row>>1)^(row>>3))&3; row = (10n+c)*16+lo so odd c flips ^2.
    const int sr  = ((lo >> 1) ^ (lo >> 3)) & 3;
    const int xqE = ((q ^ sr) & 3) * 4;          // even c
    const int xqO = ((q ^ sr ^ 2) & 3) * 4;      // odd c

    // ---- inline squash: vsp[c] = v[b=bg+lo][c][o=q*4..q*4+3], packed f16
    f16x2 vsp[10][2];
    if (PASS >= 1) {
        const int rowb = (bg + lo) * 10;
        #pragma unroll
        for (int c = 0; c < 10; ++c) {
            float4 bb = *(const float4*)(bias + c * 16 + q * 4);
            const size_t off = (size_t)(rowb + c) * 16 + q * 4;
            float4 sa = *(const float4*)(sp0a + off);
            float4 sc4 = *(const float4*)(sp0b + off);
            float t0 = (sa.x + sc4.x) * sS + bb.x;
            float t1 = (sa.y + sc4.y) * sS + bb.y;
            float t2 = (sa.z + sc4.z) * sS + bb.z;
            float t3 = (sa.w + sc4.w) * sS + bb.w;
            float n2 = xorsum4(t0*t0 + t1*t1 + t2*t2 + t3*t3);
            float sc = n2 / (1.f + n2) * rsqrtf(n2 + 1e-8f);
            float v0 = sc*t0, v1 = sc*t1, v2 = sc*t2, v3 = sc*t3;
            if (PASS == 2) {
                float4 ua = *(const float4*)(sp1a + off);
                float4 ub = *(const float4*)(sp1b + off);
                float u0 = (ua.x + ub.x) * sS + bb.x;
                float u1 = (ua.y + ub.y) * sS + bb.y;
                float u2 = (ua.z + ub.z) * sS + bb.z;
                float u3 = (ua.w + ub.w) * sS + bb.w;
                float m2 = xorsum4(u0*u0 + u1*u1 + u2*u2 + u3*u3);
                float sc2 = m2 / (1.f + m2) * rsqrtf(m2 + 1e-8f);
                v0 += sc2*u0; v1 += sc2*u1; v2 += sc2*u2; v3 += sc2*u3;
            }
            vsp[c][0] = pk(v0, v1);
            vsp[c][1] = pk(v2, v3);
        }
    }

    // ---- staging (software-pipelined), R7 pattern at half n-extent
    float4 wreg[10];
    float4 xreg[4];
    const int b_loc = tid >> 2, part = tid & 3;
    const int wcol = (((tid & 3) ^ ((tid >> 3) ^ (tid >> 5))) & 3) * 4;  // store-side swizzled col

    auto load_iter = [&](int l) {
        const float* wp = weight + (size_t)(ngrp * 2 + l) * 10240;   // 4n x 160 x 16
        #pragma unroll
        for (int k = 0; k < 10; ++k) wreg[k] = ((const float4*)wp)[tid + k * 256];
        const float* xp = poses + (size_t)(b0 + b_loc) * 32768
                          + (size_t)(ngrp * 8 + l * 4 + part) * 16;
        #pragma unroll
        for (int j = 0; j < 4; ++j) xreg[j] = ((const float4*)xp)[j];
    };
    auto store_iter = [&]() {
        #pragma unroll
        for (int k = 0; k < 10; ++k) {
            const int f = tid + k * 256;          // float4 index in [0,2560)
            *(f16x4*)&Ws[(f >> 2) * 16 + wcol] = cvt4(wreg[k]);
        }
        f16* lp = xs + b_loc * XS_ROW + part * 16;
        #pragma unroll
        for (int j = 0; j < 4; ++j) *(f16x4*)&lp[j * 4] = cvt4(xreg[j]);
    };

    f32x4 acc[10];
    #pragma unroll
    for (int c = 0; c < 10; ++c) acc[c] = (f32x4){0.f, 0.f, 0.f, 0.f};

    load_iter(0);

    for (int l = 0; l < 2; ++l) {
        __syncthreads();
        store_iter();
        if (l + 1 < 2) load_iter(l + 1);
        __syncthreads();

        #pragma unroll
        for (int n = 0; n < 4; ++n) {
            // votes^T fragments V[c][r] = votes[b=bg+lo][c][o=q*4+r] (verified R7 layout),
            // packed to f16 immediately to keep register pressure low.
            f16x4 bx = *(const f16x4*)&xs[(wtb + lo) * XS_ROW + n * 16 + q * 4];
            f16x2 Vh[10][2];
            #pragma unroll
            for (int c = 0; c < 10; ++c) {
                f16x4 aw = *(const f16x4*)&Ws[((n * 10 + c) * 16 + lo) * 16
                                              + ((c & 1) ? xqO : xqE)];
                f32x4 V = __builtin_amdgcn_mfma_f32_16x16x16f16(
                    aw, bx, (f32x4){0.f, 0.f, 0.f, 0.f}, 0, 0, 0);
                Vh[c][0] = pk(V[0], V[1]);
                Vh[c][1] = pk(V[2], V[3]);
            }

            float cfv[10];
            if (PASS >= 1) {
                // logits: fdot2 on packed votes vs vsp; packed cross-quad reduce
                float lg[10];
                #pragma unroll
                for (int cp = 0; cp < 5; ++cp) {
                    const int c0 = cp * 2, c1 = cp * 2 + 1;
                    float p0 = FDOT2(Vh[c0][0], vsp[c0][0], 0.f);
                    p0 = FDOT2(Vh[c0][1], vsp[c0][1], p0);
                    float p1 = FDOT2(Vh[c1][0], vsp[c1][0], 0.f);
                    p1 = FDOT2(Vh[c1][1], vsp[c1][1], p1);
                    f16x2 pr = xorsum4h(pk(p0, p1));
                    lg[c0] = (float)pr[0];
                    lg[c1] = (float)pr[1];
                }
                float m = lg[0];
                #pragma unroll
                for (int c = 1; c < 10; ++c) m = fmaxf(m, lg[c]);
                float sum = 0.f;
                #pragma unroll
                for (int c = 0; c < 10; ++c) { lg[c] = __expf(lg[c] - m); sum += lg[c]; }
                const float inv = 1.f / sum;
                #pragma unroll
                for (int c = 0; c < 10; ++c) cfv[c] = lg[c] * inv;
            }

            // s-accumulate straight from packed votes
            #pragma unroll
            for (int c = 0; c < 10; ++c) {
                const float w = (PASS == 0) ? 1.f : cfv[c];
                acc[c][0] = fmaf(w, (float)Vh[c][0][0], acc[c][0]);
                acc[c][1] = fmaf(w, (float)Vh[c][0][1], acc[c][1]);
                acc[c][2] = fmaf(w, (float)Vh[c][1][0], acc[c][2]);
                acc[c][3] = fmaf(w, (float)Vh[c][1][1], acc[c][3]);
            }
        }
    }

    // ---- wave-local LDS transpose (b<->o) to keep the full-line atomic flush.
    __syncthreads();                        // all waves done reading Ws/xs as f16
    float* tr = (float*)Ws + wave * 320;    // 320 floats/wave, stride-20 rows
    const float fs = (PASS == 0) ? 0.1f : 1.f;
    #pragma unroll
    for (int c = 0; c < 10; ++c) {
        // write own (b=lo, o=q*4..q*4+3); 16B-aligned b128
        *(float4*)&tr[lo * 20 + q * 4] = (float4){acc[c][0], acc[c][1], acc[c][2], acc[c][3]};
        // read (b=q*4+r, o=lo) -- wave-synchronous, in-order DS ops
        float r0 = tr[(q * 4 + 0) * 20 + lo];
        float r1 = tr[(q * 4 + 1) * 20 + lo];
        float r2 = tr[(q * 4 + 2) * 20 + lo];
        float r3 = tr[(q * 4 + 3) * 20 + lo];
        float* sp = s_dst + ((size_t)(bg + q * 4) * 10 + c) * 16 + lo;
        unsafeAtomicAdd(sp + 0 * 160, fs * r0);
        unsafeAtomicAdd(sp + 1 * 160, fs * r1);
        unsafeAtomicAdd(sp + 2 * 160, fs * r2);
        unsafeAtomicAdd(sp + 3 * 160, fs * r3);
    }
}

// final squash: 2560 rows, one (b,c) per thread (verified R3/R7).
__global__ __launch_bounds__(256)
void epi_k(const float* __restrict__ s2a, const float* __restrict__ s2b,
           const float* __restrict__ bias, float* __restrict__ out, float sS)
{
    const int t = blockIdx.x * 256 + threadIdx.x;
    if (t >= 2560) return;
    const int c = t % 10;
    const float* sp = s2a + (size_t)t * 16;
    const float* sq = s2b + (size_t)t * 16;
    const float* bp = bias + c * 16;
    float sv[16];
    float n2 = 0.f;
    #pragma unroll
    for (int o = 0; o < 16; ++o) {
        float v = (sp[o] + sq[o]) * sS + bp[o];
        sv[o] = v; n2 += v * v;
    }
    const float scale = n2 / (1.f + n2) * rsqrtf(n2 + 1e-8f);
    float a2 = 0.f;
    #pragma unroll
    for (int o = 0; o < 16; ++o) {
        float v = scale * sv[o];
        out[(size_t)t * 16 + o] = v;
        a2 += v * v;
    }
    out[40960 + t] = sqrtf(a2 + 1e-8f);
}

extern "C" void kernel_launch(void* const* d_in, const int* in_sizes, int n_in,
                              void* d_out, int out_size, void* d_ws, size_t ws_size,
                              hipStream_t stream)
{
    const float* poses  = (const float*)d_in[0];
    // d_in[1] (input_caps_activations) unused by the reference.
    const float* weight = (const float*)d_in[2];
    const float* bias   = (const float*)d_in[3];
    float* out = (float*)d_out;
    float* ws  = (float*)d_ws;

    // dual accumulator copies when ws allows (983 KB); else same-buffer 0.5x fallback.
    const bool dual  = ws_size >= (size_t)(6 * 40960 * sizeof(float));
    const int stride = dual ? 2 * 40960 : 40960;
    const int dsel   = dual ? 40960 : 0;
    const float sS   = dual ? 1.f : 0.5f;
    float* s0 = ws;
    float* s1 = ws + (size_t)stride;
    float* s2 = ws + (size_t)2 * stride;

    (void)hipMemsetAsync(d_ws, 0, (size_t)3 * stride * sizeof(float), stream);

    pass_k<0><<<1024, 256, 0, stream>>>(poses, weight, bias,
                                        nullptr, nullptr, nullptr, nullptr, s0, dsel, sS);
    pass_k<1><<<1024, 256, 0, stream>>>(poses, weight, bias,
                                        s0, s0 + dsel, nullptr, nullptr, s1, dsel, sS);
    pass_k<2><<<1024, 256, 0, stream>>>(poses, weight, bias,
                                        s0, s0 + dsel, s1, s1 + dsel, s2, dsel, sS);
    epi_k<<<10, 256, 0, stream>>>(s2, s2 + dsel, bias, out, sS);
}

// Round 2
// 515.897 us; speedup vs baseline: 1.0424x; 1.0424x over previous
//
#include <hip/hip_runtime.h>
#include <hip/hip_fp16.h>
#include <math.h>

// LinearCaps2d, BATCH=256, N = B_TYPES*H*W = 2048, C=10, POSE=16, 3 routing iters.
// R14 = R13 with the atomic-thrash fixed. R13 post-mortem: WRITE_SIZE 379 MB vs
// ~10 MB atomic payload -> per-line ping-pong between non-coherent per-XCD L2s.
//   (1) accumulator has 8 copies selected by blk&7 (~XCD id under round-robin
//       dispatch): every 128B line of copy k is touched by exactly one XCD ->
//       atomics merge in that XCD's local L2, ~one writeback per line total;
//   (2) tiny reduce_k (160 blocks) folds the 8 copies -> s0/s1 between passes
//       and re-zeroes the partials; epi_k folds the copies for s2 itself;
//   (3) keeps R13's grid 1024 (4 blocks/CU), 30208 B LDS, XOR-swizzled Ws,
//       __launch_bounds__(256,4) -- those parts verified correct and cheap.
// ws (big path): 8 partial copies + s0 + s1 = 10*40960 f32 = 1.64 MB.
// Fallback (ws < that): single copy, 3*40960 f32 = R12 footprint.

typedef _Float16 f16;
typedef _Float16 f16x2 __attribute__((ext_vector_type(2)));
typedef _Float16 f16x4 __attribute__((ext_vector_type(4)));
typedef __fp16   h16x2 __attribute__((ext_vector_type(2)));
typedef float f32x4 __attribute__((ext_vector_type(4)));

__device__ __forceinline__ f16x2 pk(float a, float b) {
    h16x2 t = __builtin_amdgcn_cvt_pkrtz(a, b);
    return __builtin_bit_cast(f16x2, t);
}

#if __has_builtin(__builtin_amdgcn_fdot2)
__device__ __forceinline__ float FDOT2(f16x2 a, f16x2 b, float c) {
    return __builtin_amdgcn_fdot2(__builtin_bit_cast(h16x2, a),
                                  __builtin_bit_cast(h16x2, b), c, false);
}
#else
__device__ __forceinline__ float FDOT2(f16x2 a, f16x2 b, float c) {
    return c + (float)a[0] * (float)b[0] + (float)a[1] * (float)b[1];
}
#endif

constexpr int XS_ROW = 76;   // f16 row stride (4n x 16 i + pad)

__device__ __forceinline__ float xorsum4(float v) {
    v += __shfl_xor(v, 16, 64);
    v += __shfl_xor(v, 32, 64);
    return v;
}

// packed f16x2 cross-quad reduction: one shfl pair for two c's (verified R11)
__device__ __forceinline__ f16x2 xorsum4h(f16x2 v) {
    union { f16x2 h; int i; } u;
    union { int i; f16x2 h; } w;
    u.h = v; w.i = __shfl_xor(u.i, 16, 64); v = v + w.h;
    u.h = v; w.i = __shfl_xor(u.i, 32, 64); v = v + w.h;
    return v;
}

__device__ __forceinline__ f16x4 cvt4(float4 w) {
    f16x2 a = pk(w.x, w.y);
    f16x2 b = pk(w.z, w.w);
    f16x4 r; r[0] = a[0]; r[1] = a[1]; r[2] = b[0]; r[3] = b[1];
    return r;
}

// grid: 1024 blocks = 256 n-groups (8 n) x 4 b-groups (64 b); 256 thr = 4 waves.
template<int PASS>
__global__ __launch_bounds__(256, 4)
void pass_k(const float* __restrict__ poses, const float* __restrict__ weight,
            const float* __restrict__ bias,
            const float* __restrict__ sp0, const float* __restrict__ sp1,
            float* __restrict__ p_base, int csel)
{
    __shared__ f16 Ws[640 * 16];       // 20480 B, XOR-swizzled columns
    __shared__ f16 xs[64 * XS_ROW];    //  9728 B

    const int tid  = threadIdx.x;
    const int blk  = blockIdx.x;
    const int ngrp = blk >> 2;          // 256 n-groups (8 n each)
    const int b0   = (blk & 3) * 64;    // 4 b-groups
    const int wave = tid >> 6;
    const int lane = tid & 63;
    const int q    = lane >> 4;
    const int lo   = lane & 15;
    const int wtb  = wave * 16;
    const int bg   = b0 + wtb;          // wave's global batch base

    // XCD-private accumulator copy: blk&7 tracks the round-robin XCD mapping,
    // so each copy's lines are touched by one XCD's L2 only (no ping-pong).
    float* s_dst = p_base + (size_t)(blk & 7) * csel;

    // swizzle constants (lane-constant): physical col-quad = q ^ sigma(row),
    // sigma(row) = ((row>>1)^(row>>3))&3; row = (10n+c)*16+lo so odd c flips ^2.
    const int sr  = ((lo >> 1) ^ (lo >> 3)) & 3;
    const int xqE = ((q ^ sr) & 3) * 4;          // even c
    const int xqO = ((q ^ sr ^ 2) & 3) * 4;      // odd c

    // ---- inline squash: vsp[c] = v[b=bg+lo][c][o=q*4..q*4+3], packed f16
    f16x2 vsp[10][2];
    if (PASS >= 1) {
        const int rowb = (bg + lo) * 10;
        #pragma unroll
        for (int c = 0; c < 10; ++c) {
            float4 bb = *(const float4*)(bias + c * 16 + q * 4);
            const size_t off = (size_t)(rowb + c) * 16 + q * 4;
            float4 sa = *(const float4*)(sp0 + off);
            float t0 = sa.x + bb.x, t1 = sa.y + bb.y;
            float t2 = sa.z + bb.z, t3 = sa.w + bb.w;
            float n2 = xorsum4(t0*t0 + t1*t1 + t2*t2 + t3*t3);
            float sc = n2 / (1.f + n2) * rsqrtf(n2 + 1e-8f);
            float v0 = sc*t0, v1 = sc*t1, v2 = sc*t2, v3 = sc*t3;
            if (PASS == 2) {
                float4 ua = *(const float4*)(sp1 + off);
                float u0 = ua.x + bb.x, u1 = ua.y + bb.y;
                float u2 = ua.z + bb.z, u3 = ua.w + bb.w;
                float m2 = xorsum4(u0*u0 + u1*u1 + u2*u2 + u3*u3);
                float sc2 = m2 / (1.f + m2) * rsqrtf(m2 + 1e-8f);
                v0 += sc2*u0; v1 += sc2*u1; v2 += sc2*u2; v3 += sc2*u3;
            }
            vsp[c][0] = pk(v0, v1);
            vsp[c][1] = pk(v2, v3);
        }
    }

    // ---- staging (software-pipelined), R7 pattern at 8-n extent
    float4 wreg[10];
    float4 xreg[4];
    const int b_loc = tid >> 2, part = tid & 3;
    const int wcol = (((tid & 3) ^ ((tid >> 3) ^ (tid >> 5))) & 3) * 4;  // store-side swizzled col

    auto load_iter = [&](int l) {
        const float* wp = weight + (size_t)(ngrp * 2 + l) * 10240;   // 4n x 160 x 16
        #pragma unroll
        for (int k = 0; k < 10; ++k) wreg[k] = ((const float4*)wp)[tid + k * 256];
        const float* xp = poses + (size_t)(b0 + b_loc) * 32768
                          + (size_t)(ngrp * 8 + l * 4 + part) * 16;
        #pragma unroll
        for (int j = 0; j < 4; ++j) xreg[j] = ((const float4*)xp)[j];
    };
    auto store_iter = [&]() {
        #pragma unroll
        for (int k = 0; k < 10; ++k) {
            const int f = tid + k * 256;          // float4 index in [0,2560)
            *(f16x4*)&Ws[(f >> 2) * 16 + wcol] = cvt4(wreg[k]);
        }
        f16* lp = xs + b_loc * XS_ROW + part * 16;
        #pragma unroll
        for (int j = 0; j < 4; ++j) *(f16x4*)&lp[j * 4] = cvt4(xreg[j]);
    };

    f32x4 acc[10];
    #pragma unroll
    for (int c = 0; c < 10; ++c) acc[c] = (f32x4){0.f, 0.f, 0.f, 0.f};

    load_iter(0);

    for (int l = 0; l < 2; ++l) {
        __syncthreads();
        store_iter();
        if (l + 1 < 2) load_iter(l + 1);
        __syncthreads();

        #pragma unroll
        for (int n = 0; n < 4; ++n) {
            // votes^T fragments V[c][r] = votes[b=bg+lo][c][o=q*4+r] (verified R7 layout),
            // packed to f16 immediately to keep register pressure low.
            f16x4 bx = *(const f16x4*)&xs[(wtb + lo) * XS_ROW + n * 16 + q * 4];
            f16x2 Vh[10][2];
            #pragma unroll
            for (int c = 0; c < 10; ++c) {
                f16x4 aw = *(const f16x4*)&Ws[((n * 10 + c) * 16 + lo) * 16
                                              + ((c & 1) ? xqO : xqE)];
                f32x4 V = __builtin_amdgcn_mfma_f32_16x16x16f16(
                    aw, bx, (f32x4){0.f, 0.f, 0.f, 0.f}, 0, 0, 0);
                Vh[c][0] = pk(V[0], V[1]);
                Vh[c][1] = pk(V[2], V[3]);
            }

            float cfv[10];
            if (PASS >= 1) {
                // logits: fdot2 on packed votes vs vsp; packed cross-quad reduce
                float lg[10];
                #pragma unroll
                for (int cp = 0; cp < 5; ++cp) {
                    const int c0 = cp * 2, c1 = cp * 2 + 1;
                    float p0 = FDOT2(Vh[c0][0], vsp[c0][0], 0.f);
                    p0 = FDOT2(Vh[c0][1], vsp[c0][1], p0);
                    float p1 = FDOT2(Vh[c1][0], vsp[c1][0], 0.f);
                    p1 = FDOT2(Vh[c1][1], vsp[c1][1], p1);
                    f16x2 pr = xorsum4h(pk(p0, p1));
                    lg[c0] = (float)pr[0];
                    lg[c1] = (float)pr[1];
                }
                float m = lg[0];
                #pragma unroll
                for (int c = 1; c < 10; ++c) m = fmaxf(m, lg[c]);
                float sum = 0.f;
                #pragma unroll
                for (int c = 0; c < 10; ++c) { lg[c] = __expf(lg[c] - m); sum += lg[c]; }
                const float inv = 1.f / sum;
                #pragma unroll
                for (int c = 0; c < 10; ++c) cfv[c] = lg[c] * inv;
            }

            // s-accumulate straight from packed votes
            #pragma unroll
            for (int c = 0; c < 10; ++c) {
                const float w = (PASS == 0) ? 1.f : cfv[c];
                acc[c][0] = fmaf(w, (float)Vh[c][0][0], acc[c][0]);
                acc[c][1] = fmaf(w, (float)Vh[c][0][1], acc[c][1]);
                acc[c][2] = fmaf(w, (float)Vh[c][1][0], acc[c][2]);
                acc[c][3] = fmaf(w, (float)Vh[c][1][1], acc[c][3]);
            }
        }
    }

    // ---- wave-local LDS transpose (b<->o) to keep the full-line atomic flush.
    __syncthreads();                        // all waves done reading Ws/xs as f16
    float* tr = (float*)Ws + wave * 320;    // 320 floats/wave, stride-20 rows
    const float fs = (PASS == 0) ? 0.1f : 1.f;
    #pragma unroll
    for (int c = 0; c < 10; ++c) {
        // write own (b=lo, o=q*4..q*4+3); 16B-aligned b128
        *(float4*)&tr[lo * 20 + q * 4] = (float4){acc[c][0], acc[c][1], acc[c][2], acc[c][3]};
        // read (b=q*4+r, o=lo) -- wave-synchronous, in-order DS ops
        float r0 = tr[(q * 4 + 0) * 20 + lo];
        float r1 = tr[(q * 4 + 1) * 20 + lo];
        float r2 = tr[(q * 4 + 2) * 20 + lo];
        float r3 = tr[(q * 4 + 3) * 20 + lo];
        float* sp = s_dst + ((size_t)(bg + q * 4) * 10 + c) * 16 + lo;
        unsafeAtomicAdd(sp + 0 * 160, fs * r0);
        unsafeAtomicAdd(sp + 1 * 160, fs * r1);
        unsafeAtomicAdd(sp + 2 * 160, fs * r2);
        unsafeAtomicAdd(sp + 3 * 160, fs * r3);
    }
}

// fold the 8 XCD-private copies -> s_r, and re-zero the used partial slots.
// Copy k only holds addresses with bgrp == k&3 (b0 = blk&3), parities k>>2.
__global__ __launch_bounds__(256)
void reduce_k(float* __restrict__ p, float* __restrict__ s_r, int csel)
{
    const int t = blockIdx.x * 256 + threadIdx.x;
    if (t >= 40960) return;
    const int row  = t >> 4;        // b*10 + c
    const int bgrp = (row / 10) >> 6;
    if (csel) {
        float* pa = p + (size_t)bgrp * csel;
        float* pb = p + (size_t)(bgrp + 4) * csel;
        s_r[t] = pa[t] + pb[t];
        pa[t] = 0.f;
        pb[t] = 0.f;
    } else {
        s_r[t] = p[t];
        p[t] = 0.f;
    }
}

// final squash: 2560 rows, one (b,c) per thread; folds the s2 copies itself.
__global__ __launch_bounds__(256)
void epi_k(const float* __restrict__ p, const float* __restrict__ bias,
           float* __restrict__ out, int csel)
{
    const int t = blockIdx.x * 256 + threadIdx.x;
    if (t >= 2560) return;
    const int c = t % 10;
    const int bgrp = (t / 10) >> 6;
    const float* pa = p + (size_t)bgrp * csel + (size_t)t * 16;
    const float* pb = p + (size_t)(bgrp + 4) * csel + (size_t)t * 16;
    const float* bp = bias + c * 16;
    float sv[16];
    float n2 = 0.f;
    #pragma unroll
    for (int o = 0; o < 16; ++o) {
        float v = pa[o] + (csel ? pb[o] : 0.f) + bp[o];
        sv[o] = v; n2 += v * v;
    }
    const float scale = n2 / (1.f + n2) * rsqrtf(n2 + 1e-8f);
    float a2 = 0.f;
    #pragma unroll
    for (int o = 0; o < 16; ++o) {
        float v = scale * sv[o];
        out[(size_t)t * 16 + o] = v;
        a2 += v * v;
    }
    out[40960 + t] = sqrtf(a2 + 1e-8f);
}

extern "C" void kernel_launch(void* const* d_in, const int* in_sizes, int n_in,
                              void* d_out, int out_size, void* d_ws, size_t ws_size,
                              hipStream_t stream)
{
    const float* poses  = (const float*)d_in[0];
    // d_in[1] (input_caps_activations) unused by the reference.
    const float* weight = (const float*)d_in[2];
    const float* bias   = (const float*)d_in[3];
    float* out = (float*)d_out;
    float* ws  = (float*)d_ws;

    // big path: 8 XCD-private partial copies + s0 + s1 (10*40960 f32 = 1.64 MB).
    // small path: single copy (3*40960 f32 = R12 footprint, R12-equivalent flow).
    const bool big = ws_size >= (size_t)10 * 40960 * sizeof(float);
    const int  csel  = big ? 40960 : 0;
    const int  ncopy = big ? 8 : 1;
    float* p  = ws;
    float* s0 = ws + (size_t)ncopy * 40960;
    float* s1 = s0 + 40960;

    (void)hipMemsetAsync(p, 0, (size_t)ncopy * 40960 * sizeof(float), stream);

    pass_k<0><<<1024, 256, 0, stream>>>(poses, weight, bias, nullptr, nullptr, p, csel);
    reduce_k<<<160, 256, 0, stream>>>(p, s0, csel);
    pass_k<1><<<1024, 256, 0, stream>>>(poses, weight, bias, s0, nullptr, p, csel);
    reduce_k<<<160, 256, 0, stream>>>(p, s1, csel);
    pass_k<2><<<1024, 256, 0, stream>>>(poses, weight, bias, s0, s1, p, csel);
    epi_k<<<10, 256, 0, stream>>>(p, bias, out, csel);
}

// Round 3
// 340.915 us; speedup vs baseline: 1.5775x; 1.5133x over previous
//
#include <hip/hip_runtime.h>
#include <hip/hip_fp16.h>
#include <math.h>

// LinearCaps2d, BATCH=256, N = B_TYPES*H*W = 2048, C=10, POSE=16, 3 routing iters.
// R15: R13/R14 post-mortem -- launch_bounds(256,4) halved the unified reg pool
// (512/SIMD -> 128/wave) => VGPR_Count 64, massive scratch spills (=the 500 MB
// of "mystery" HBM traffic and the 3x slowdown). Atomics were never the issue
// (R12 writes ~= payload; R14 8-copy change = null result).
//   (1) __launch_bounds__(256,3): ~170 regs/wave cap, no spills, 3 blocks/CU;
//   (2) f16-convert staging at LOAD (wregh/xregh = 14 regs vs 56 f32) so the
//       allocator can even reach 128 -> 4 blocks/CU;
//   (3) single accumulator + no reduce_k (R14 proved copies don't matter);
//   (4) XCD-aware mapping: ngrp=(blk>>5)*8+(blk&7), bsel=(blk>>3)&3 -- the 4
//       b-group blocks sharing one weight slice land on the SAME XCD L2;
//   (5) keep grid 1024 (8n/block, 2 l-iters), 30208 B LDS, swizzled Ws.
// ws: s0,s1,s2 [40960] f32 (491 KB).

typedef _Float16 f16;
typedef _Float16 f16x2 __attribute__((ext_vector_type(2)));
typedef _Float16 f16x4 __attribute__((ext_vector_type(4)));
typedef __fp16   h16x2 __attribute__((ext_vector_type(2)));
typedef float f32x4 __attribute__((ext_vector_type(4)));

__device__ __forceinline__ f16x2 pk(float a, float b) {
    h16x2 t = __builtin_amdgcn_cvt_pkrtz(a, b);
    return __builtin_bit_cast(f16x2, t);
}

#if __has_builtin(__builtin_amdgcn_fdot2)
__device__ __forceinline__ float FDOT2(f16x2 a, f16x2 b, float c) {
    return __builtin_amdgcn_fdot2(__builtin_bit_cast(h16x2, a),
                                  __builtin_bit_cast(h16x2, b), c, false);
}
#else
__device__ __forceinline__ float FDOT2(f16x2 a, f16x2 b, float c) {
    return c + (float)a[0] * (float)b[0] + (float)a[1] * (float)b[1];
}
#endif

constexpr int XS_ROW = 76;   // f16 row stride (4n x 16 i + pad)

__device__ __forceinline__ float xorsum4(float v) {
    v += __shfl_xor(v, 16, 64);
    v += __shfl_xor(v, 32, 64);
    return v;
}

// packed f16x2 cross-quad reduction: one shfl pair for two c's (verified R11)
__device__ __forceinline__ f16x2 xorsum4h(f16x2 v) {
    union { f16x2 h; int i; } u;
    union { int i; f16x2 h; } w;
    u.h = v; w.i = __shfl_xor(u.i, 16, 64); v = v + w.h;
    u.h = v; w.i = __shfl_xor(u.i, 32, 64); v = v + w.h;
    return v;
}

__device__ __forceinline__ f16x4 cvt4(float4 w) {
    f16x2 a = pk(w.x, w.y);
    f16x2 b = pk(w.z, w.w);
    f16x4 r; r[0] = a[0]; r[1] = a[1]; r[2] = b[0]; r[3] = b[1];
    return r;
}

// grid: 1024 blocks = 256 n-groups (8 n) x 4 b-groups (64 b); 256 thr = 4 waves.
// XCD-aware mapping: partners of one n-group are blk, blk+8, blk+16, blk+24
// (same XCD under round-robin dispatch) so the weight slice is fetched once.
template<int PASS>
__global__ __launch_bounds__(256, 3)
void pass_k(const float* __restrict__ poses, const float* __restrict__ weight,
            const float* __restrict__ bias,
            const float* __restrict__ sp0, const float* __restrict__ sp1,
            float* __restrict__ s_dst)
{
    __shared__ f16 Ws[640 * 16];       // 20480 B, XOR-swizzled columns
    __shared__ f16 xs[64 * XS_ROW];    //  9728 B

    const int tid  = threadIdx.x;
    const int blk  = blockIdx.x;
    const int ngrp = ((blk >> 5) << 3) | (blk & 7);   // [0,256), 8 n each
    const int b0   = ((blk >> 3) & 3) * 64;           // 4 b-groups
    const int wave = tid >> 6;
    const int lane = tid & 63;
    const int q    = lane >> 4;
    const int lo   = lane & 15;
    const int wtb  = wave * 16;
    const int bg   = b0 + wtb;          // wave's global batch base

    // swizzle constants (lane-constant): physical col-quad = q ^ sigma(row),
    // sigma(row) = ((row>>1)^(row>>3))&3; row = (10n+c)*16+lo so odd c flips ^2.
    const int sr  = ((lo >> 1) ^ (lo >> 3)) & 3;
    const int xqE = ((q ^ sr) & 3) * 4;          // even c
    const int xqO = ((q ^ sr ^ 2) & 3) * 4;      // odd c

    // ---- inline squash: vsp[c] = v[b=bg+lo][c][o=q*4..q*4+3], packed f16
    f16x2 vsp[10][2];
    if (PASS >= 1) {
        const int rowb = (bg + lo) * 10;
        #pragma unroll
        for (int c = 0; c < 10; ++c) {
            float4 bb = *(const float4*)(bias + c * 16 + q * 4);
            const size_t off = (size_t)(rowb + c) * 16 + q * 4;
            float4 sa = *(const float4*)(sp0 + off);
            float t0 = sa.x + bb.x, t1 = sa.y + bb.y;
            float t2 = sa.z + bb.z, t3 = sa.w + bb.w;
            float n2 = xorsum4(t0*t0 + t1*t1 + t2*t2 + t3*t3);
            float sc = n2 / (1.f + n2) * rsqrtf(n2 + 1e-8f);
            float v0 = sc*t0, v1 = sc*t1, v2 = sc*t2, v3 = sc*t3;
            if (PASS == 2) {
                float4 ua = *(const float4*)(sp1 + off);
                float u0 = ua.x + bb.x, u1 = ua.y + bb.y;
                float u2 = ua.z + bb.z, u3 = ua.w + bb.w;
                float m2 = xorsum4(u0*u0 + u1*u1 + u2*u2 + u3*u3);
                float sc2 = m2 / (1.f + m2) * rsqrtf(m2 + 1e-8f);
                v0 += sc2*u0; v1 += sc2*u1; v2 += sc2*u2; v3 += sc2*u3;
            }
            vsp[c][0] = pk(v0, v1);
            vsp[c][1] = pk(v2, v3);
        }
    }

    // ---- staging (software-pipelined); f16-convert at LOAD to keep the
    // cross-compute live set at 14 regs (wregh+xregh) instead of 56.
    f16x4 wregh[10];
    f16x4 xregh[4];
    const int b_loc = tid >> 2, part = tid & 3;
    const int wcol = (((tid & 3) ^ ((tid >> 3) ^ (tid >> 5))) & 3) * 4;  // store-side swizzled col

    auto load_iter = [&](int l) {
        const float* wp = weight + (size_t)(ngrp * 2 + l) * 10240;   // 4n x 160 x 16
        #pragma unroll
        for (int k = 0; k < 10; ++k) {
            float4 t = ((const float4*)wp)[tid + k * 256];
            wregh[k] = cvt4(t);
        }
        const float* xp = poses + (size_t)(b0 + b_loc) * 32768
                          + (size_t)(ngrp * 8 + l * 4 + part) * 16;
        #pragma unroll
        for (int j = 0; j < 4; ++j) {
            float4 t = ((const float4*)xp)[j];
            xregh[j] = cvt4(t);
        }
    };
    auto store_iter = [&]() {
        #pragma unroll
        for (int k = 0; k < 10; ++k) {
            const int f = tid + k * 256;          // float4 index in [0,2560)
            *(f16x4*)&Ws[(f >> 2) * 16 + wcol] = wregh[k];
        }
        f16* lp = xs + b_loc * XS_ROW + part * 16;
        #pragma unroll
        for (int j = 0; j < 4; ++j) *(f16x4*)&lp[j * 4] = xregh[j];
    };

    f32x4 acc[10];
    #pragma unroll
    for (int c = 0; c < 10; ++c) acc[c] = (f32x4){0.f, 0.f, 0.f, 0.f};

    load_iter(0);

    for (int l = 0; l < 2; ++l) {
        __syncthreads();
        store_iter();
        if (l + 1 < 2) load_iter(l + 1);
        __syncthreads();

        #pragma unroll
        for (int n = 0; n < 4; ++n) {
            // votes^T fragments V[c][r] = votes[b=bg+lo][c][o=q*4+r] (verified R7 layout),
            // packed to f16 immediately to keep register pressure low.
            f16x4 bx = *(const f16x4*)&xs[(wtb + lo) * XS_ROW + n * 16 + q * 4];
            f16x2 Vh[10][2];
            #pragma unroll
            for (int c = 0; c < 10; ++c) {
                f16x4 aw = *(const f16x4*)&Ws[((n * 10 + c) * 16 + lo) * 16
                                              + ((c & 1) ? xqO : xqE)];
                f32x4 V = __builtin_amdgcn_mfma_f32_16x16x16f16(
                    aw, bx, (f32x4){0.f, 0.f, 0.f, 0.f}, 0, 0, 0);
                Vh[c][0] = pk(V[0], V[1]);
                Vh[c][1] = pk(V[2], V[3]);
            }

            float cfv[10];
            if (PASS >= 1) {
                // logits: fdot2 on packed votes vs vsp; packed cross-quad reduce
                float lg[10];
                #pragma unroll
                for (int cp = 0; cp < 5; ++cp) {
                    const int c0 = cp * 2, c1 = cp * 2 + 1;
                    float p0 = FDOT2(Vh[c0][0], vsp[c0][0], 0.f);
                    p0 = FDOT2(Vh[c0][1], vsp[c0][1], p0);
                    float p1 = FDOT2(Vh[c1][0], vsp[c1][0], 0.f);
                    p1 = FDOT2(Vh[c1][1], vsp[c1][1], p1);
                    f16x2 pr = xorsum4h(pk(p0, p1));
                    lg[c0] = (float)pr[0];
                    lg[c1] = (float)pr[1];
                }
                float m = lg[0];
                #pragma unroll
                for (int c = 1; c < 10; ++c) m = fmaxf(m, lg[c]);
                float sum = 0.f;
                #pragma unroll
                for (int c = 0; c < 10; ++c) { lg[c] = __expf(lg[c] - m); sum += lg[c]; }
                const float inv = 1.f / sum;
                #pragma unroll
                for (int c = 0; c < 10; ++c) cfv[c] = lg[c] * inv;
            }

            // s-accumulate straight from packed votes
            #pragma unroll
            for (int c = 0; c < 10; ++c) {
                const float w = (PASS == 0) ? 1.f : cfv[c];
                acc[c][0] = fmaf(w, (float)Vh[c][0][0], acc[c][0]);
                acc[c][1] = fmaf(w, (float)Vh[c][0][1], acc[c][1]);
                acc[c][2] = fmaf(w, (float)Vh[c][1][0], acc[c][2]);
                acc[c][3] = fmaf(w, (float)Vh[c][1][1], acc[c][3]);
            }
        }
    }

    // ---- wave-local LDS transpose (b<->o) to keep the full-line atomic flush.
    __syncthreads();                        // all waves done reading Ws/xs as f16
    float* tr = (float*)Ws + wave * 320;    // 320 floats/wave, stride-20 rows
    const float fs = (PASS == 0) ? 0.1f : 1.f;
    #pragma unroll
    for (int c = 0; c < 10; ++c) {
        // write own (b=lo, o=q*4..q*4+3); 16B-aligned b128
        *(float4*)&tr[lo * 20 + q * 4] = (float4){acc[c][0], acc[c][1], acc[c][2], acc[c][3]};
        // read (b=q*4+r, o=lo) -- wave-synchronous, in-order DS ops
        float r0 = tr[(q * 4 + 0) * 20 + lo];
        float r1 = tr[(q * 4 + 1) * 20 + lo];
        float r2 = tr[(q * 4 + 2) * 20 + lo];
        float r3 = tr[(q * 4 + 3) * 20 + lo];
        float* sp = s_dst + ((size_t)(bg + q * 4) * 10 + c) * 16 + lo;
        unsafeAtomicAdd(sp + 0 * 160, fs * r0);
        unsafeAtomicAdd(sp + 1 * 160, fs * r1);
        unsafeAtomicAdd(sp + 2 * 160, fs * r2);
        unsafeAtomicAdd(sp + 3 * 160, fs * r3);
    }
}

// final squash: 2560 rows, one (b,c) per thread (verified R3/R7).
__global__ __launch_bounds__(256)
void epi_k(const float* __restrict__ s2, const float* __restrict__ bias,
           float* __restrict__ out)
{
    const int t = blockIdx.x * 256 + threadIdx.x;
    if (t >= 2560) return;
    const int c = t % 10;
    const float* sp = s2 + (size_t)t * 16;
    const float* bp = bias + c * 16;
    float sv[16];
    float n2 = 0.f;
    #pragma unroll
    for (int o = 0; o < 16; ++o) { float v = sp[o] + bp[o]; sv[o] = v; n2 += v * v; }
    const float scale = n2 / (1.f + n2) * rsqrtf(n2 + 1e-8f);
    float a2 = 0.f;
    #pragma unroll
    for (int o = 0; o < 16; ++o) {
        float v = scale * sv[o];
        out[(size_t)t * 16 + o] = v;
        a2 += v * v;
    }
    out[40960 + t] = sqrtf(a2 + 1e-8f);
}

extern "C" void kernel_launch(void* const* d_in, const int* in_sizes, int n_in,
                              void* d_out, int out_size, void* d_ws, size_t ws_size,
                              hipStream_t stream)
{
    const float* poses  = (const float*)d_in[0];
    // d_in[1] (input_caps_activations) unused by the reference.
    const float* weight = (const float*)d_in[2];
    const float* bias   = (const float*)d_in[3];
    float* out = (float*)d_out;
    float* s0 = (float*)d_ws;
    float* s1 = s0 + 40960;
    float* s2 = s1 + 40960;

    (void)hipMemsetAsync(d_ws, 0, 3 * 40960 * sizeof(float), stream);

    pass_k<0><<<1024, 256, 0, stream>>>(poses, weight, bias, nullptr, nullptr, s0);
    pass_k<1><<<1024, 256, 0, stream>>>(poses, weight, bias, s0, nullptr, s1);
    pass_k<2><<<1024, 256, 0, stream>>>(poses, weight, bias, s0, s1, s2);
    epi_k<<<10, 256, 0, stream>>>(s2, bias, out);
}

// Round 4
// 247.483 us; speedup vs baseline: 2.1730x; 1.3775x over previous
//
#include <hip/hip_runtime.h>
#include <hip/hip_fp16.h>
#include <math.h>

// LinearCaps2d, BATCH=256, N = B_TYPES*H*W = 2048, C=10, POSE=16, 3 routing iters.
// R16: isolate the register-cap poison. Evidence across R12-R15: spill traffic
// tracks the launch_bounds cap monotonically (64 regs->628 MB, 84->330 MB,
// 128->90 MB per pass). hipcc's 2nd launch_bounds arg is a MINIMUM; at (256,3)
// it targeted 6 waves/EU (512/6=84 regs) and spilled. (256,2) -> 128 regs is
// the proven spill-free point (R12). R14's 8-copy null was spill-confounded;
// R12's WRITE=26MB ~= atomic payload proves the atomic flush was never the issue.
//   (1) __launch_bounds__(256,2): 128-reg budget, no spills; residency then
//       comes from usage/LDS/grid -> 4 blocks/CU (16 waves, 2x R12);
//   (2) keep grid 1024 (8n/block, 2 l-iters) = the occupancy lever;
//   (3) revert to R12's consecutive-partner mapping (ngrp=blk>>2) whose 62 MB
//       FETCH proved L3 absorbs the 4-way weight share;
//   (4) keep f16-convert-at-load staging (14 live regs vs 56), swizzled Ws,
//       30208 B LDS, single accumulator, no reduce_k.
// ws: s0,s1,s2 [40960] f32 (491 KB).

typedef _Float16 f16;
typedef _Float16 f16x2 __attribute__((ext_vector_type(2)));
typedef _Float16 f16x4 __attribute__((ext_vector_type(4)));
typedef __fp16   h16x2 __attribute__((ext_vector_type(2)));
typedef float f32x4 __attribute__((ext_vector_type(4)));

__device__ __forceinline__ f16x2 pk(float a, float b) {
    h16x2 t = __builtin_amdgcn_cvt_pkrtz(a, b);
    return __builtin_bit_cast(f16x2, t);
}

#if __has_builtin(__builtin_amdgcn_fdot2)
__device__ __forceinline__ float FDOT2(f16x2 a, f16x2 b, float c) {
    return __builtin_amdgcn_fdot2(__builtin_bit_cast(h16x2, a),
                                  __builtin_bit_cast(h16x2, b), c, false);
}
#else
__device__ __forceinline__ float FDOT2(f16x2 a, f16x2 b, float c) {
    return c + (float)a[0] * (float)b[0] + (float)a[1] * (float)b[1];
}
#endif

constexpr int XS_ROW = 76;   // f16 row stride (4n x 16 i + pad)

__device__ __forceinline__ float xorsum4(float v) {
    v += __shfl_xor(v, 16, 64);
    v += __shfl_xor(v, 32, 64);
    return v;
}

// packed f16x2 cross-quad reduction: one shfl pair for two c's (verified R11)
__device__ __forceinline__ f16x2 xorsum4h(f16x2 v) {
    union { f16x2 h; int i; } u;
    union { int i; f16x2 h; } w;
    u.h = v; w.i = __shfl_xor(u.i, 16, 64); v = v + w.h;
    u.h = v; w.i = __shfl_xor(u.i, 32, 64); v = v + w.h;
    return v;
}

__device__ __forceinline__ f16x4 cvt4(float4 w) {
    f16x2 a = pk(w.x, w.y);
    f16x2 b = pk(w.z, w.w);
    f16x4 r; r[0] = a[0]; r[1] = a[1]; r[2] = b[0]; r[3] = b[1];
    return r;
}

// grid: 1024 blocks = 256 n-groups (8 n) x 4 b-groups (64 b); 256 thr = 4 waves.
// Consecutive partners (blk&~3..blk|3) share one weight slice; L3 absorbs the
// 4-way re-fetch (proven R12: FETCH ~= unique bytes).
template<int PASS>
__global__ __launch_bounds__(256, 2)
void pass_k(const float* __restrict__ poses, const float* __restrict__ weight,
            const float* __restrict__ bias,
            const float* __restrict__ sp0, const float* __restrict__ sp1,
            float* __restrict__ s_dst)
{
    __shared__ f16 Ws[640 * 16];       // 20480 B, XOR-swizzled columns
    __shared__ f16 xs[64 * XS_ROW];    //  9728 B

    const int tid  = threadIdx.x;
    const int blk  = blockIdx.x;
    const int ngrp = blk >> 2;          // 256 n-groups (8 n each)
    const int b0   = (blk & 3) * 64;    // 4 b-groups
    const int wave = tid >> 6;
    const int lane = tid & 63;
    const int q    = lane >> 4;
    const int lo   = lane & 15;
    const int wtb  = wave * 16;
    const int bg   = b0 + wtb;          // wave's global batch base

    // swizzle constants (lane-constant): physical col-quad = q ^ sigma(row),
    // sigma(row) = ((row>>1)^(row>>3))&3; row = (10n+c)*16+lo so odd c flips ^2.
    const int sr  = ((lo >> 1) ^ (lo >> 3)) & 3;
    const int xqE = ((q ^ sr) & 3) * 4;          // even c
    const int xqO = ((q ^ sr ^ 2) & 3) * 4;      // odd c

    // ---- inline squash: vsp[c] = v[b=bg+lo][c][o=q*4..q*4+3], packed f16
    f16x2 vsp[10][2];
    if (PASS >= 1) {
        const int rowb = (bg + lo) * 10;
        #pragma unroll
        for (int c = 0; c < 10; ++c) {
            float4 bb = *(const float4*)(bias + c * 16 + q * 4);
            const size_t off = (size_t)(rowb + c) * 16 + q * 4;
            float4 sa = *(const float4*)(sp0 + off);
            float t0 = sa.x + bb.x, t1 = sa.y + bb.y;
            float t2 = sa.z + bb.z, t3 = sa.w + bb.w;
            float n2 = xorsum4(t0*t0 + t1*t1 + t2*t2 + t3*t3);
            float sc = n2 / (1.f + n2) * rsqrtf(n2 + 1e-8f);
            float v0 = sc*t0, v1 = sc*t1, v2 = sc*t2, v3 = sc*t3;
            if (PASS == 2) {
                float4 ua = *(const float4*)(sp1 + off);
                float u0 = ua.x + bb.x, u1 = ua.y + bb.y;
                float u2 = ua.z + bb.z, u3 = ua.w + bb.w;
                float m2 = xorsum4(u0*u0 + u1*u1 + u2*u2 + u3*u3);
                float sc2 = m2 / (1.f + m2) * rsqrtf(m2 + 1e-8f);
                v0 += sc2*u0; v1 += sc2*u1; v2 += sc2*u2; v3 += sc2*u3;
            }
            vsp[c][0] = pk(v0, v1);
            vsp[c][1] = pk(v2, v3);
        }
    }

    // ---- staging (software-pipelined); f16-convert at LOAD to keep the
    // cross-compute live set at 14 regs (wregh+xregh) instead of 56.
    f16x4 wregh[10];
    f16x4 xregh[4];
    const int b_loc = tid >> 2, part = tid & 3;
    const int wcol = (((tid & 3) ^ ((tid >> 3) ^ (tid >> 5))) & 3) * 4;  // store-side swizzled col

    auto load_iter = [&](int l) {
        const float* wp = weight + (size_t)(ngrp * 2 + l) * 10240;   // 4n x 160 x 16
        #pragma unroll
        for (int k = 0; k < 10; ++k) {
            float4 t = ((const float4*)wp)[tid + k * 256];
            wregh[k] = cvt4(t);
        }
        const float* xp = poses + (size_t)(b0 + b_loc) * 32768
                          + (size_t)(ngrp * 8 + l * 4 + part) * 16;
        #pragma unroll
        for (int j = 0; j < 4; ++j) {
            float4 t = ((const float4*)xp)[j];
            xregh[j] = cvt4(t);
        }
    };
    auto store_iter = [&]() {
        #pragma unroll
        for (int k = 0; k < 10; ++k) {
            const int f = tid + k * 256;          // float4 index in [0,2560)
            *(f16x4*)&Ws[(f >> 2) * 16 + wcol] = wregh[k];
        }
        f16* lp = xs + b_loc * XS_ROW + part * 16;
        #pragma unroll
        for (int j = 0; j < 4; ++j) *(f16x4*)&lp[j * 4] = xregh[j];
    };

    f32x4 acc[10];
    #pragma unroll
    for (int c = 0; c < 10; ++c) acc[c] = (f32x4){0.f, 0.f, 0.f, 0.f};

    load_iter(0);

    for (int l = 0; l < 2; ++l) {
        __syncthreads();
        store_iter();
        if (l + 1 < 2) load_iter(l + 1);
        __syncthreads();

        #pragma unroll
        for (int n = 0; n < 4; ++n) {
            // votes^T fragments V[c][r] = votes[b=bg+lo][c][o=q*4+r] (verified R7 layout),
            // packed to f16 immediately to keep register pressure low.
            f16x4 bx = *(const f16x4*)&xs[(wtb + lo) * XS_ROW + n * 16 + q * 4];
            f16x2 Vh[10][2];
            #pragma unroll
            for (int c = 0; c < 10; ++c) {
                f16x4 aw = *(const f16x4*)&Ws[((n * 10 + c) * 16 + lo) * 16
                                              + ((c & 1) ? xqO : xqE)];
                f32x4 V = __builtin_amdgcn_mfma_f32_16x16x16f16(
                    aw, bx, (f32x4){0.f, 0.f, 0.f, 0.f}, 0, 0, 0);
                Vh[c][0] = pk(V[0], V[1]);
                Vh[c][1] = pk(V[2], V[3]);
            }

            float cfv[10];
            if (PASS >= 1) {
                // logits: fdot2 on packed votes vs vsp; packed cross-quad reduce
                float lg[10];
                #pragma unroll
                for (int cp = 0; cp < 5; ++cp) {
                    const int c0 = cp * 2, c1 = cp * 2 + 1;
                    float p0 = FDOT2(Vh[c0][0], vsp[c0][0], 0.f);
                    p0 = FDOT2(Vh[c0][1], vsp[c0][1], p0);
                    float p1 = FDOT2(Vh[c1][0], vsp[c1][0], 0.f);
                    p1 = FDOT2(Vh[c1][1], vsp[c1][1], p1);
                    f16x2 pr = xorsum4h(pk(p0, p1));
                    lg[c0] = (float)pr[0];
                    lg[c1] = (float)pr[1];
                }
                float m = lg[0];
                #pragma unroll
                for (int c = 1; c < 10; ++c) m = fmaxf(m, lg[c]);
                float sum = 0.f;
                #pragma unroll
                for (int c = 0; c < 10; ++c) { lg[c] = __expf(lg[c] - m); sum += lg[c]; }
                const float inv = 1.f / sum;
                #pragma unroll
                for (int c = 0; c < 10; ++c) cfv[c] = lg[c] * inv;
            }

            // s-accumulate straight from packed votes
            #pragma unroll
            for (int c = 0; c < 10; ++c) {
                const float w = (PASS == 0) ? 1.f : cfv[c];
                acc[c][0] = fmaf(w, (float)Vh[c][0][0], acc[c][0]);
                acc[c][1] = fmaf(w, (float)Vh[c][0][1], acc[c][1]);
                acc[c][2] = fmaf(w, (float)Vh[c][1][0], acc[c][2]);
                acc[c][3] = fmaf(w, (float)Vh[c][1][1], acc[c][3]);
            }
        }
    }

    // ---- wave-local LDS transpose (b<->o) to keep the full-line atomic flush.
    __syncthreads();                        // all waves done reading Ws/xs as f16
    float* tr = (float*)Ws + wave * 320;    // 320 floats/wave, stride-20 rows
    const float fs = (PASS == 0) ? 0.1f : 1.f;
    #pragma unroll
    for (int c = 0; c < 10; ++c) {
        // write own (b=lo, o=q*4..q*4+3); 16B-aligned b128
        *(float4*)&tr[lo * 20 + q * 4] = (float4){acc[c][0], acc[c][1], acc[c][2], acc[c][3]};
        // read (b=q*4+r, o=lo) -- wave-synchronous, in-order DS ops
        float r0 = tr[(q * 4 + 0) * 20 + lo];
        float r1 = tr[(q * 4 + 1) * 20 + lo];
        float r2 = tr[(q * 4 + 2) * 20 + lo];
        float r3 = tr[(q * 4 + 3) * 20 + lo];
        float* sp = s_dst + ((size_t)(bg + q * 4) * 10 + c) * 16 + lo;
        unsafeAtomicAdd(sp + 0 * 160, fs * r0);
        unsafeAtomicAdd(sp + 1 * 160, fs * r1);
        unsafeAtomicAdd(sp + 2 * 160, fs * r2);
        unsafeAtomicAdd(sp + 3 * 160, fs * r3);
    }
}

// final squash: 2560 rows, one (b,c) per thread (verified R3/R7).
__global__ __launch_bounds__(256)
void epi_k(const float* __restrict__ s2, const float* __restrict__ bias,
           float* __restrict__ out)
{
    const int t = blockIdx.x * 256 + threadIdx.x;
    if (t >= 2560) return;
    const int c = t % 10;
    const float* sp = s2 + (size_t)t * 16;
    const float* bp = bias + c * 16;
    float sv[16];
    float n2 = 0.f;
    #pragma unroll
    for (int o = 0; o < 16; ++o) { float v = sp[o] + bp[o]; sv[o] = v; n2 += v * v; }
    const float scale = n2 / (1.f + n2) * rsqrtf(n2 + 1e-8f);
    float a2 = 0.f;
    #pragma unroll
    for (int o = 0; o < 16; ++o) {
        float v = scale * sv[o];
        out[(size_t)t * 16 + o] = v;
        a2 += v * v;
    }
    out[40960 + t] = sqrtf(a2 + 1e-8f);
}

extern "C" void kernel_launch(void* const* d_in, const int* in_sizes, int n_in,
                              void* d_out, int out_size, void* d_ws, size_t ws_size,
                              hipStream_t stream)
{
    const float* poses  = (const float*)d_in[0];
    // d_in[1] (input_caps_activations) unused by the reference.
    const float* weight = (const float*)d_in[2];
    const float* bias   = (const float*)d_in[3];
    float* out = (float*)d_out;
    float* s0 = (float*)d_ws;
    float* s1 = s0 + 40960;
    float* s2 = s1 + 40960;

    (void)hipMemsetAsync(d_ws, 0, 3 * 40960 * sizeof(float), stream);

    pass_k<0><<<1024, 256, 0, stream>>>(poses, weight, bias, nullptr, nullptr, s0);
    pass_k<1><<<1024, 256, 0, stream>>>(poses, weight, bias, s0, nullptr, s1);
    pass_k<2><<<1024, 256, 0, stream>>>(poses, weight, bias, s0, s1, s2);
    epi_k<<<10, 256, 0, stream>>>(s2, bias, out);
}